// Round 3
// 10849.324 us; speedup vs baseline: 1.0885x; 1.0885x over previous
//
#include <hip/hip_runtime.h>
#include <hip/hip_bf16.h>

typedef unsigned short u16;
typedef unsigned int u32;
typedef __attribute__((ext_vector_type(4))) unsigned int u32x4;
typedef __attribute__((ext_vector_type(8))) short bf16x8;
typedef __attribute__((ext_vector_type(4))) float f32x4;

__device__ __forceinline__ u16 f2bf(float f) {
    u32 u = __float_as_uint(f);
    u32 r = (u + 0x7fffu + ((u >> 16) & 1u)) >> 16;
    return (u16)r;
}
__device__ __forceinline__ float bf2f(u16 b) {
    return __uint_as_float(((u32)b) << 16);
}
__device__ __forceinline__ float sigm(float x) {
    return 1.0f / (1.0f + __expf(-x));
}
__device__ __forceinline__ float tanh_fast(float x) {
    return 1.0f - 2.0f / (1.0f + __expf(2.0f * x));
}

// ---------------------------------------------------------------- casts
__global__ void cast_bf16_kernel(const float* __restrict__ in, u16* __restrict__ out, int n) {
    int i = (blockIdx.x * blockDim.x + threadIdx.x) * 4;
    int stride = gridDim.x * blockDim.x * 4;
    for (; i + 3 < n; i += stride) {
        float4 v = *(const float4*)&in[i];
        ushort4 o;
        o.x = f2bf(v.x); o.y = f2bf(v.y); o.z = f2bf(v.z); o.w = f2bf(v.w);
        *(ushort4*)&out[i] = o;
    }
}

// zero the 8 KB flag region (harness poisons ws with 0xAA every launch!)
__global__ void init_flags_kernel(u32* f) {
    f[blockIdx.x * 256 + threadIdx.x] = 0u;
}

// ---------------------------------------------------------------- GEMM (TN)
// A: [M,K] bf16 row-major; B: [N,K] bf16 row-major.
// mode 1: out bf16 xg, row permuted (m=b*1024+t -> t*32+b), COLUMN permuted
//         unit-major: col = (n&1023)*4 + (n>>10); +bias0[n]+bias1[n]
// mode 2: out fp32 keys/values split (+bias)
#define BM 128
#define BN 128
#define BK 64

__global__ __launch_bounds__(256) void gemm_tn(
    const u16* __restrict__ A, const u16* __restrict__ Bm,
    int M, int N, int K,
    const float* __restrict__ bias0, const float* __restrict__ bias1,
    u16* __restrict__ outB, float* __restrict__ outF, int mode)
{
    __shared__ __align__(16) u16 As[BM][BK];
    __shared__ __align__(16) u16 Bs[BN][BK];
    const int tid = threadIdx.x;
    const int lane = tid & 63;
    const int w = tid >> 6;
    const int wm = w >> 1, wn = w & 1;
    const int m0 = blockIdx.y * BM, n0 = blockIdx.x * BN;

    const u16* Aptr = A + (size_t)m0 * K;
    const u16* Bptr = Bm + (size_t)n0 * K;

    f32x4 acc[4][4];
#pragma unroll
    for (int i = 0; i < 4; i++)
#pragma unroll
        for (int j = 0; j < 4; j++)
            acc[i][j] = (f32x4){0.f, 0.f, 0.f, 0.f};

    u32x4 ra[4], rb[4];
#pragma unroll
    for (int i = 0; i < 4; i++) {
        int cid = i * 256 + tid;
        int r = cid >> 3, s = cid & 7;
        int gc = s ^ (r & 7);
        ra[i] = *(const u32x4*)&Aptr[(size_t)r * K + gc * 8];
        rb[i] = *(const u32x4*)&Bptr[(size_t)r * K + gc * 8];
    }

    for (int kb = 0; kb < K; kb += BK) {
        __syncthreads();
#pragma unroll
        for (int i = 0; i < 4; i++) {
            int cid = i * 256 + tid;
            int r = cid >> 3, s = cid & 7;
            *(u32x4*)&As[r][s * 8] = ra[i];
            *(u32x4*)&Bs[r][s * 8] = rb[i];
        }
        __syncthreads();
        if (kb + BK < K) {
            int kn = kb + BK;
#pragma unroll
            for (int i = 0; i < 4; i++) {
                int cid = i * 256 + tid;
                int r = cid >> 3, s = cid & 7;
                int gc = s ^ (r & 7);
                ra[i] = *(const u32x4*)&Aptr[(size_t)r * K + kn + gc * 8];
                rb[i] = *(const u32x4*)&Bptr[(size_t)r * K + kn + gc * 8];
            }
        }
#pragma unroll
        for (int kk = 0; kk < 2; kk++) {
            bf16x8 af[4], bfr[4];
#pragma unroll
            for (int mi = 0; mi < 4; mi++) {
                int rr = wm * 64 + mi * 16 + (lane & 15);
                int q = kk * 4 + (lane >> 4);
                af[mi] = *(const bf16x8*)&As[rr][(q ^ (rr & 7)) * 8];
            }
#pragma unroll
            for (int ni = 0; ni < 4; ni++) {
                int rr = wn * 64 + ni * 16 + (lane & 15);
                int q = kk * 4 + (lane >> 4);
                bfr[ni] = *(const bf16x8*)&Bs[rr][(q ^ (rr & 7)) * 8];
            }
#pragma unroll
            for (int mi = 0; mi < 4; mi++)
#pragma unroll
                for (int ni = 0; ni < 4; ni++)
                    acc[mi][ni] = __builtin_amdgcn_mfma_f32_16x16x32_bf16(
                        af[mi], bfr[ni], acc[mi][ni], 0, 0, 0);
        }
    }

#pragma unroll
    for (int mi = 0; mi < 4; mi++) {
#pragma unroll
        for (int ni = 0; ni < 4; ni++) {
            int n = n0 + wn * 64 + ni * 16 + (lane & 15);
#pragma unroll
            for (int v = 0; v < 4; v++) {
                int m = m0 + wm * 64 + mi * 16 + (lane >> 4) * 4 + v;
                float val = acc[mi][ni][v];
                if (mode == 1) {
                    val += bias0[n] + bias1[n];
                    int tt = m & 1023, b = m >> 10;
                    int col = ((n & 1023) << 2) | (n >> 10);   // unit-major, gate-minor
                    outB[(size_t)(tt * 32 + b) * 4096 + col] = f2bf(val);
                } else {
                    if (n < 512) {
                        outF[(size_t)m * 512 + n] = val + bias0[n];
                    } else {
                        outF[16777216u + (size_t)m * 512 + (n - 512)] = val + bias1[n - 512];
                    }
                }
            }
        }
    }
}

// ---------------------------------------------------------------- recurrence
// 64 blocks x 256 thr (4 waves), REGULAR launch (no coop: we never grid-sync;
// 64 blocks with 64 KB LDS on 256 CUs are trivially all-resident, and
// hipLaunchCooperativeKernel's occupancy validation -- prime suspect for the
// silent phase-2 skip in rounds 1-2 -- is bypassed entirely).
// Block rank owns hidden units [rank*16, rank*16+16) = 64 gate cols; each wave
// holds breg[32] (round-0-proven register profile, 16 cols x K=1024).
// Coherence protocol byte-for-byte from the round-0 PASSED kernel:
// agent-scope relaxed atomic h/flag stores, acquire-agent fence before staged
// plain loads. vs baseline: poll fan-in 128x128 -> 64x64 lines (4x less),
// h-staging 8 MB/step -> 4 MB/step (2x less).
__global__ __launch_bounds__(256, 1) void lstm_rec(
    const u16* __restrict__ Whh,   // [4096][1024] bf16 (gate-row major, original)
    const u16* __restrict__ xg,    // [(t*32+b)][4096] bf16, col = unit*4+gate
    u16* __restrict__ hs,          // [(b*1024+t)][1024] bf16
    u32* __restrict__ flags)       // 64 flags at stride 16 dwords, init 0
{
    __shared__ __align__(16) u16 hl[32][1024];   // 64 KB staged h(t-1), chunk-swizzled

    const int tid = threadIdx.x;
    const int lane = tid & 63;
    const int w = tid >> 6;
    const int rank = blockIdx.x;               // 0..63

    // ---- W_hh slice preload: wave w owns block-local cols [w*16, w*16+16)
    // (col = local_unit*4 + gate, local_unit = rank*16 + (col>>2))
    bf16x8 breg[32];
    {
        int col = w * 16 + (lane & 15);                       // 0..63
        int gr = (col & 3) * 1024 + rank * 16 + (col >> 2);   // global gate row
        const u16* wp = Whh + (size_t)gr * 1024 + (lane >> 4) * 8;
#pragma unroll
        for (int kk = 0; kk < 32; kk++)
            breg[kk] = *(const bf16x8*)&wp[kk * 32];
    }

    // post-transpose lane identity
    int mpr[2];
    mpr[0] = ((lane >> 4) << 2) + (lane & 3);   // batch 0..15
    mpr[1] = mpr[0] + 16;                       // batch 16..31
    const int ul = w * 4 + ((lane & 15) >> 2);  // local unit 0..15

    const u16* xgp[2];
    xgp[0] = xg + (size_t)mpr[0] * 4096 + (rank * 16 + ul) * 4;
    xgp[1] = xg + (size_t)mpr[1] * 4096 + (rank * 16 + ul) * 4;

    ushort4 xq[2], xqn[2];
    xq[0] = *(const ushort4*)xgp[0];   // t = 0 (i,f,g,o contiguous)
    xq[1] = *(const ushort4*)xgp[1];

    float c[2] = {0.f, 0.f};

    for (int t = 0; t < 1024; t++) {
        float g4[2][4];
        if (t > 0) {
            // prefetch next step's xg quads FIRST: LLC latency hides under the
            // flag wait; consumed next iteration
            if (t < 1023) {
                xqn[0] = *(const ushort4*)(xgp[0] + (size_t)(t + 1) * 131072);
                xqn[1] = *(const ushort4*)(xgp[1] + (size_t)(t + 1) * 131072);
            }

            // ---- wait for all 64 blocks to have published h(t-1)
            if (w == 0) {
                const u32* fp = flags + lane * 16;
                const u32 tgt = (u32)t;
                for (;;) {
                    u32 fv = __hip_atomic_load(fp, __ATOMIC_RELAXED, __HIP_MEMORY_SCOPE_AGENT);
                    if (__all((int)(fv >= tgt))) break;
                }
            }
            __syncthreads();
            __builtin_amdgcn_fence(__ATOMIC_ACQUIRE, "agent");  // inv stale hs lines

            // ---- stage h(t-1): 64 KB coalesced, chunk-swizzled (round-0 loop)
#pragma unroll
            for (int i = 0; i < 16; i++) {
                int cid = i * 256 + tid;
                int bb = cid >> 7, cc = cid & 127;
                u32x4 v = *(const u32x4*)&hs[((size_t)(bb << 10) + (t - 1)) * 1024 + cc * 8];
                *(u32x4*)&hl[bb][(cc ^ (bb & 7)) * 8] = v;
            }
            __syncthreads();

            // ---- GEMM: D[batch 0..31][block col w*16..w*16+16), K = 1024
            f32x4 acc0 = (f32x4){0.f, 0.f, 0.f, 0.f};
            f32x4 acc1 = (f32x4){0.f, 0.f, 0.f, 0.f};
            {
                const int r0 = lane & 15;
                const int qb = lane >> 4;
#pragma unroll
                for (int kk = 0; kk < 32; kk++) {
                    int q = kk * 4 + qb;
                    bf16x8 a0 = *(const bf16x8*)&hl[r0][(q ^ (r0 & 7)) * 8];
                    bf16x8 a1 = *(const bf16x8*)&hl[r0 + 16][(q ^ (r0 & 7)) * 8];
                    acc0 = __builtin_amdgcn_mfma_f32_16x16x32_bf16(a0, breg[kk], acc0, 0, 0, 0);
                    acc1 = __builtin_amdgcn_mfma_f32_16x16x32_bf16(a1, breg[kk], acc1, 0, 0, 0);
                }
            }

            // ---- 4x4 lane-register transpose (round-0-proven):
            // before: lane&3 = gate, reg = batch-sub; after: lane&3 = batch-sub, reg = gate
#pragma unroll
            for (int mi = 0; mi < 2; mi++) {
                float gg[4], tmp[4];
#pragma unroll
                for (int v = 0; v < 4; v++) gg[v] = (mi == 0) ? acc0[v] : acc1[v];
#pragma unroll
                for (int v = 0; v < 4; v++) tmp[v] = __shfl_xor(gg[v ^ 1], 1, 64);
#pragma unroll
                for (int v = 0; v < 4; v++) if ((v & 1) != (lane & 1)) gg[v] = tmp[v];
#pragma unroll
                for (int v = 0; v < 4; v++) tmp[v] = __shfl_xor(gg[v ^ 2], 2, 64);
#pragma unroll
                for (int v = 0; v < 4; v++) if ((v & 2) != (lane & 2)) gg[v] = tmp[v];
#pragma unroll
                for (int v = 0; v < 4; v++) g4[mi][v] = gg[v];
            }
        } else {
            xqn[0] = *(const ushort4*)(xgp[0] + 131072);
            xqn[1] = *(const ushort4*)(xgp[1] + 131072);
#pragma unroll
            for (int mi = 0; mi < 2; mi++)
#pragma unroll
                for (int v = 0; v < 4; v++) g4[mi][v] = 0.f;
        }

        // ---- activation + state + publish (PyTorch gate order i,f,g,o)
#pragma unroll
        for (int mi = 0; mi < 2; mi++) {
            float gi = g4[mi][0] + bf2f(xq[mi].x);
            float gf = g4[mi][1] + bf2f(xq[mi].y);
            float gG = g4[mi][2] + bf2f(xq[mi].z);
            float go = g4[mi][3] + bf2f(xq[mi].w);
            float iv = sigm(gi), fv = sigm(gf), gv = tanh_fast(gG), ov = sigm(go);
            c[mi] = fv * c[mi] + iv * gv;
            float h = ov * tanh_fast(c[mi]);
            // pack units (ul, ul+1) of same batch (lanes L, L^4) into a dword;
            // agent-scope atomic store (write-through to coherence point)
            u32 mine = (u32)f2bf(h);
            u32 other = (u32)__shfl_xor((int)mine, 4, 64);
            if (((lane >> 2) & 1) == 0) {   // even local unit
                u32 packed = mine | (other << 16);
                u32* p = (u32*)&hs[((size_t)(mpr[mi] << 10) + t) * 1024 + rank * 16 + ul];
                __hip_atomic_store(p, packed, __ATOMIC_RELAXED, __HIP_MEMORY_SCOPE_AGENT);
            }
        }

        __syncthreads();   // per-wave vmcnt(0) before barrier -> h stores complete
        if (t < 1023 && tid == 0)
            __hip_atomic_store(&flags[rank * 16], (u32)(t + 1),
                               __ATOMIC_RELAXED, __HIP_MEMORY_SCOPE_AGENT);
        xq[0] = xqn[0];
        xq[1] = xqn[1];
    }
}

// ---------------------------------------------------------------- launch
extern "C" void kernel_launch(void* const* d_in, const int* in_sizes, int n_in,
                              void* d_out, int out_size, void* d_ws, size_t ws_size,
                              hipStream_t stream) {
    const float* x     = (const float*)d_in[0];
    const float* W_ih  = (const float*)d_in[1];
    const float* W_hh  = (const float*)d_in[2];
    const float* b_ih  = (const float*)d_in[3];
    const float* b_hh  = (const float*)d_in[4];
    const float* W_key = (const float*)d_in[5];
    const float* b_key = (const float*)d_in[6];
    const float* W_val = (const float*)d_in[7];
    const float* b_val = (const float*)d_in[8];
    float* out = (float*)d_out;

    char* ws = (char*)d_ws;
    u16* xg    = (u16*)(ws);                        // 256 MB  [S*32][4096]
    u16* hs    = (u16*)(ws + 268435456ull);         //  64 MB  [32*1024][1024]
    u16* xb    = (u16*)(ws + 335544320ull);         //  32 MB  x bf16
    u16* whh   = (u16*)(ws + 369098752ull);         //   8 MB
    u16* wih   = (u16*)(ws + 377487360ull);         //   4 MB
    u16* wkv   = (u16*)(ws + 381681664ull);         //   2 MB  [Wkey;Wval]
    u32* flags = (u32*)(ws + 383778816ull);         //   8 KB  barrier flags

    cast_bf16_kernel<<<1024, 256, 0, stream>>>(x, xb, 32 * 1024 * 512);
    cast_bf16_kernel<<<256, 256, 0, stream>>>(W_ih, wih, 4096 * 512);
    cast_bf16_kernel<<<256, 256, 0, stream>>>(W_hh, whh, 4096 * 1024);
    cast_bf16_kernel<<<64, 256, 0, stream>>>(W_key, wkv, 512 * 1024);
    cast_bf16_kernel<<<64, 256, 0, stream>>>(W_val, wkv + 512 * 1024, 512 * 1024);
    init_flags_kernel<<<8, 256, 0, stream>>>(flags);

    // phase 1: xg = x @ W_ih^T + b_ih + b_hh  (row+col permuted bf16)
    gemm_tn<<<dim3(4096 / BN, 32768 / BM), 256, 0, stream>>>(
        xb, wih, 32768, 4096, 512, b_ih, b_hh, xg, nullptr, 1);

    // phase 2: recurrence — 64 blocks, REGULAR launch (trivially co-resident)
    lstm_rec<<<dim3(64), dim3(256), 0, stream>>>(whh, xg, hs, flags);

    // phase 3: keys/values = hs @ [Wkey;Wval]^T + bias
    gemm_tn<<<dim3(1024 / BN, 32768 / BM), 256, 0, stream>>>(
        hs, wkv, 32768, 1024, 1024, b_key, b_val, nullptr, out, 2);
}

// Round 4
// 5924.511 us; speedup vs baseline: 1.9934x; 1.8313x over previous
//
#include <hip/hip_runtime.h>
#include <hip/hip_bf16.h>

typedef unsigned short u16;
typedef unsigned int u32;
typedef __attribute__((ext_vector_type(4))) unsigned int u32x4;
typedef __attribute__((ext_vector_type(8))) short bf16x8;
typedef __attribute__((ext_vector_type(4))) float f32x4;

__device__ __forceinline__ u16 f2bf(float f) {
    u32 u = __float_as_uint(f);
    u32 r = (u + 0x7fffu + ((u >> 16) & 1u)) >> 16;
    return (u16)r;
}
__device__ __forceinline__ float bf2f(u16 b) {
    return __uint_as_float(((u32)b) << 16);
}
__device__ __forceinline__ float sigm(float x) {
    return 1.0f / (1.0f + __expf(-x));
}
__device__ __forceinline__ float tanh_fast(float x) {
    return 1.0f - 2.0f / (1.0f + __expf(2.0f * x));
}

// ---------------------------------------------------------------- casts
__global__ void cast_bf16_kernel(const float* __restrict__ in, u16* __restrict__ out, int n) {
    int i = (blockIdx.x * blockDim.x + threadIdx.x) * 4;
    int stride = gridDim.x * blockDim.x * 4;
    for (; i + 3 < n; i += stride) {
        float4 v = *(const float4*)&in[i];
        ushort4 o;
        o.x = f2bf(v.x); o.y = f2bf(v.y); o.z = f2bf(v.z); o.w = f2bf(v.w);
        *(ushort4*)&out[i] = o;
    }
}

// zero the 8 KB flag region (harness poisons ws with 0xAA every launch!)
__global__ void init_flags_kernel(u32* f) {
    f[blockIdx.x * 256 + threadIdx.x] = 0u;
}

// ---------------------------------------------------------------- GEMM (TN)
// A: [M,K] bf16 row-major; B: [N,K] bf16 row-major.
// mode 1: out bf16 xg, row permuted (m=b*1024+t -> t*32+b), COLUMN permuted
//         unit-major: col = (n&1023)*4 + (n>>10); +bias0[n]+bias1[n]
// mode 2: out fp32 keys/values split (+bias)
#define BM 128
#define BN 128
#define BK 64

__global__ __launch_bounds__(256) void gemm_tn(
    const u16* __restrict__ A, const u16* __restrict__ Bm,
    int M, int N, int K,
    const float* __restrict__ bias0, const float* __restrict__ bias1,
    u16* __restrict__ outB, float* __restrict__ outF, int mode)
{
    __shared__ __align__(16) u16 As[BM][BK];
    __shared__ __align__(16) u16 Bs[BN][BK];
    const int tid = threadIdx.x;
    const int lane = tid & 63;
    const int w = tid >> 6;
    const int wm = w >> 1, wn = w & 1;
    const int m0 = blockIdx.y * BM, n0 = blockIdx.x * BN;

    const u16* Aptr = A + (size_t)m0 * K;
    const u16* Bptr = Bm + (size_t)n0 * K;

    f32x4 acc[4][4];
#pragma unroll
    for (int i = 0; i < 4; i++)
#pragma unroll
        for (int j = 0; j < 4; j++)
            acc[i][j] = (f32x4){0.f, 0.f, 0.f, 0.f};

    u32x4 ra[4], rb[4];
#pragma unroll
    for (int i = 0; i < 4; i++) {
        int cid = i * 256 + tid;
        int r = cid >> 3, s = cid & 7;
        int gc = s ^ (r & 7);
        ra[i] = *(const u32x4*)&Aptr[(size_t)r * K + gc * 8];
        rb[i] = *(const u32x4*)&Bptr[(size_t)r * K + gc * 8];
    }

    for (int kb = 0; kb < K; kb += BK) {
        __syncthreads();
#pragma unroll
        for (int i = 0; i < 4; i++) {
            int cid = i * 256 + tid;
            int r = cid >> 3, s = cid & 7;
            *(u32x4*)&As[r][s * 8] = ra[i];
            *(u32x4*)&Bs[r][s * 8] = rb[i];
        }
        __syncthreads();
        if (kb + BK < K) {
            int kn = kb + BK;
#pragma unroll
            for (int i = 0; i < 4; i++) {
                int cid = i * 256 + tid;
                int r = cid >> 3, s = cid & 7;
                int gc = s ^ (r & 7);
                ra[i] = *(const u32x4*)&Aptr[(size_t)r * K + kn + gc * 8];
                rb[i] = *(const u32x4*)&Bptr[(size_t)r * K + kn + gc * 8];
            }
        }
#pragma unroll
        for (int kk = 0; kk < 2; kk++) {
            bf16x8 af[4], bfr[4];
#pragma unroll
            for (int mi = 0; mi < 4; mi++) {
                int rr = wm * 64 + mi * 16 + (lane & 15);
                int q = kk * 4 + (lane >> 4);
                af[mi] = *(const bf16x8*)&As[rr][(q ^ (rr & 7)) * 8];
            }
#pragma unroll
            for (int ni = 0; ni < 4; ni++) {
                int rr = wn * 64 + ni * 16 + (lane & 15);
                int q = kk * 4 + (lane >> 4);
                bfr[ni] = *(const bf16x8*)&Bs[rr][(q ^ (rr & 7)) * 8];
            }
#pragma unroll
            for (int mi = 0; mi < 4; mi++)
#pragma unroll
                for (int ni = 0; ni < 4; ni++)
                    acc[mi][ni] = __builtin_amdgcn_mfma_f32_16x16x32_bf16(
                        af[mi], bfr[ni], acc[mi][ni], 0, 0, 0);
        }
    }

#pragma unroll
    for (int mi = 0; mi < 4; mi++) {
#pragma unroll
        for (int ni = 0; ni < 4; ni++) {
            int n = n0 + wn * 64 + ni * 16 + (lane & 15);
#pragma unroll
            for (int v = 0; v < 4; v++) {
                int m = m0 + wm * 64 + mi * 16 + (lane >> 4) * 4 + v;
                float val = acc[mi][ni][v];
                if (mode == 1) {
                    val += bias0[n] + bias1[n];
                    int tt = m & 1023, b = m >> 10;
                    int col = ((n & 1023) << 2) | (n >> 10);   // unit-major, gate-minor
                    outB[(size_t)(tt * 32 + b) * 4096 + col] = f2bf(val);
                } else {
                    if (n < 512) {
                        outF[(size_t)m * 512 + n] = val + bias0[n];
                    } else {
                        outF[16777216u + (size_t)m * 512 + (n - 512)] = val + bias1[n - 512];
                    }
                }
            }
        }
    }
}

// ---------------------------------------------------------------- recurrence
// 64 blocks x 256 thr (4 waves), regular launch (round-3 PASSED structure).
// ROUND-4 CHANGE (single variable): the staged h(t-1) loads are now
// device-coherent (`global_load_dwordx4 ... sc0 sc1` -> bypass L1/L2, read
// the LLC coherence point directly, same as the flag poll), and the per-step
// `fence(ACQUIRE, "agent")` is DELETED. The fence invalidated the whole XCD
// L2 every step x 8 resident blocks/XCD -- prime suspect for the fixed
// ~24k-cycle/step serial chain (MfmaUtil+VALUBusy ~1.5% -> 98.5% wait) and
// for the FETCH_SIZE anomaly (423 MB vs ~265 minimal: L2-nuked xg re-fetch).
// Every racing access is now explicitly coherent: h stores sc1, flag
// store/poll sc1, h loads sc1. L2 stays warm for the xg/Whh streams.
__global__ __launch_bounds__(256, 1) void lstm_rec(
    const u16* __restrict__ Whh,   // [4096][1024] bf16 (gate-row major, original)
    const u16* __restrict__ xg,    // [(t*32+b)][4096] bf16, col = unit*4+gate
    u16* __restrict__ hs,          // [(b*1024+t)][1024] bf16
    u32* __restrict__ flags)       // 64 flags at stride 16 dwords, init 0
{
    __shared__ __align__(16) u16 hl[32][1024];   // 64 KB staged h(t-1), chunk-swizzled

    const int tid = threadIdx.x;
    const int lane = tid & 63;
    const int w = tid >> 6;
    const int rank = blockIdx.x;               // 0..63

    // ---- W_hh slice preload: wave w owns block-local cols [w*16, w*16+16)
    // (col = local_unit*4 + gate, local_unit = rank*16 + (col>>2))
    bf16x8 breg[32];
    {
        int col = w * 16 + (lane & 15);                       // 0..63
        int gr = (col & 3) * 1024 + rank * 16 + (col >> 2);   // global gate row
        const u16* wp = Whh + (size_t)gr * 1024 + (lane >> 4) * 8;
#pragma unroll
        for (int kk = 0; kk < 32; kk++)
            breg[kk] = *(const bf16x8*)&wp[kk * 32];
    }

    // post-transpose lane identity
    int mpr[2];
    mpr[0] = ((lane >> 4) << 2) + (lane & 3);   // batch 0..15
    mpr[1] = mpr[0] + 16;                       // batch 16..31
    const int ul = w * 4 + ((lane & 15) >> 2);  // local unit 0..15

    const u16* xgp[2];
    xgp[0] = xg + (size_t)mpr[0] * 4096 + (rank * 16 + ul) * 4;
    xgp[1] = xg + (size_t)mpr[1] * 4096 + (rank * 16 + ul) * 4;

    ushort4 xq[2], xqn[2];
    xq[0] = *(const ushort4*)xgp[0];   // t = 0 (i,f,g,o contiguous)
    xq[1] = *(const ushort4*)xgp[1];

    float c[2] = {0.f, 0.f};

    for (int t = 0; t < 1024; t++) {
        float g4[2][4];
        if (t > 0) {
            // prefetch next step's xg quads FIRST: latency hides under the
            // flag wait; consumed next iteration
            if (t < 1023) {
                xqn[0] = *(const ushort4*)(xgp[0] + (size_t)(t + 1) * 131072);
                xqn[1] = *(const ushort4*)(xgp[1] + (size_t)(t + 1) * 131072);
            }

            // ---- wait for all 64 blocks to have published h(t-1)
            if (w == 0) {
                const u32* fp = flags + lane * 16;
                const u32 tgt = (u32)t;
                for (;;) {
                    u32 fv = __hip_atomic_load(fp, __ATOMIC_RELAXED, __HIP_MEMORY_SCOPE_AGENT);
                    if (__all((int)(fv >= tgt))) break;
                }
            }
            __syncthreads();
            // NO agent-acquire fence: staged loads below are sc0 sc1
            // (device-coherent, bypass L1/L2) so stale lines are impossible.

            // ---- stage h(t-1): 64 KB coalesced, chunk-swizzled LDS layout
            u32x4 sv[16];
#pragma unroll
            for (int i = 0; i < 16; i++) {
                int cid = i * 256 + tid;
                int bb = cid >> 7, cc = cid & 127;
                const u16* src = &hs[((size_t)(bb << 10) + (t - 1)) * 1024 + cc * 8];
                asm volatile("global_load_dwordx4 %0, %1, off sc0 sc1"
                             : "=&v"(sv[i]) : "v"(src) : "memory");
            }
            asm volatile("s_waitcnt vmcnt(0)" ::: "memory");
#pragma unroll
            for (int i = 0; i < 16; i++) {
                int cid = i * 256 + tid;
                int bb = cid >> 7, cc = cid & 127;
                *(u32x4*)&hl[bb][(cc ^ (bb & 7)) * 8] = sv[i];
            }
            __syncthreads();

            // ---- GEMM: D[batch 0..31][block col w*16..w*16+16), K = 1024
            f32x4 acc0 = (f32x4){0.f, 0.f, 0.f, 0.f};
            f32x4 acc1 = (f32x4){0.f, 0.f, 0.f, 0.f};
            {
                const int r0 = lane & 15;
                const int qb = lane >> 4;
#pragma unroll
                for (int kk = 0; kk < 32; kk++) {
                    int q = kk * 4 + qb;
                    bf16x8 a0 = *(const bf16x8*)&hl[r0][(q ^ (r0 & 7)) * 8];
                    bf16x8 a1 = *(const bf16x8*)&hl[r0 + 16][(q ^ (r0 & 7)) * 8];
                    acc0 = __builtin_amdgcn_mfma_f32_16x16x32_bf16(a0, breg[kk], acc0, 0, 0, 0);
                    acc1 = __builtin_amdgcn_mfma_f32_16x16x32_bf16(a1, breg[kk], acc1, 0, 0, 0);
                }
            }

            // ---- 4x4 lane-register transpose (round-0-proven):
            // before: lane&3 = gate, reg = batch-sub; after: lane&3 = batch-sub, reg = gate
#pragma unroll
            for (int mi = 0; mi < 2; mi++) {
                float gg[4], tmp[4];
#pragma unroll
                for (int v = 0; v < 4; v++) gg[v] = (mi == 0) ? acc0[v] : acc1[v];
#pragma unroll
                for (int v = 0; v < 4; v++) tmp[v] = __shfl_xor(gg[v ^ 1], 1, 64);
#pragma unroll
                for (int v = 0; v < 4; v++) if ((v & 1) != (lane & 1)) gg[v] = tmp[v];
#pragma unroll
                for (int v = 0; v < 4; v++) tmp[v] = __shfl_xor(gg[v ^ 2], 2, 64);
#pragma unroll
                for (int v = 0; v < 4; v++) if ((v & 2) != (lane & 2)) gg[v] = tmp[v];
#pragma unroll
                for (int v = 0; v < 4; v++) g4[mi][v] = gg[v];
            }
        } else {
            xqn[0] = *(const ushort4*)(xgp[0] + 131072);
            xqn[1] = *(const ushort4*)(xgp[1] + 131072);
#pragma unroll
            for (int mi = 0; mi < 2; mi++)
#pragma unroll
                for (int v = 0; v < 4; v++) g4[mi][v] = 0.f;
        }

        // ---- activation + state + publish (PyTorch gate order i,f,g,o)
#pragma unroll
        for (int mi = 0; mi < 2; mi++) {
            float gi = g4[mi][0] + bf2f(xq[mi].x);
            float gf = g4[mi][1] + bf2f(xq[mi].y);
            float gG = g4[mi][2] + bf2f(xq[mi].z);
            float go = g4[mi][3] + bf2f(xq[mi].w);
            float iv = sigm(gi), fv = sigm(gf), gv = tanh_fast(gG), ov = sigm(go);
            c[mi] = fv * c[mi] + iv * gv;
            float h = ov * tanh_fast(c[mi]);
            // pack units (ul, ul+1) of same batch (lanes L, L^4) into a dword;
            // agent-scope atomic store (write-through to coherence point)
            u32 mine = (u32)f2bf(h);
            u32 other = (u32)__shfl_xor((int)mine, 4, 64);
            if (((lane >> 2) & 1) == 0) {   // even local unit
                u32 packed = mine | (other << 16);
                u32* p = (u32*)&hs[((size_t)(mpr[mi] << 10) + t) * 1024 + rank * 16 + ul];
                __hip_atomic_store(p, packed, __ATOMIC_RELAXED, __HIP_MEMORY_SCOPE_AGENT);
            }
        }

        __syncthreads();   // per-wave vmcnt(0) before barrier -> h stores complete
        if (t < 1023 && tid == 0)
            __hip_atomic_store(&flags[rank * 16], (u32)(t + 1),
                               __ATOMIC_RELAXED, __HIP_MEMORY_SCOPE_AGENT);
        xq[0] = xqn[0];
        xq[1] = xqn[1];
    }
}

// ---------------------------------------------------------------- launch
extern "C" void kernel_launch(void* const* d_in, const int* in_sizes, int n_in,
                              void* d_out, int out_size, void* d_ws, size_t ws_size,
                              hipStream_t stream) {
    const float* x     = (const float*)d_in[0];
    const float* W_ih  = (const float*)d_in[1];
    const float* W_hh  = (const float*)d_in[2];
    const float* b_ih  = (const float*)d_in[3];
    const float* b_hh  = (const float*)d_in[4];
    const float* W_key = (const float*)d_in[5];
    const float* b_key = (const float*)d_in[6];
    const float* W_val = (const float*)d_in[7];
    const float* b_val = (const float*)d_in[8];
    float* out = (float*)d_out;

    char* ws = (char*)d_ws;
    u16* xg    = (u16*)(ws);                        // 256 MB  [S*32][4096]
    u16* hs    = (u16*)(ws + 268435456ull);         //  64 MB  [32*1024][1024]
    u16* xb    = (u16*)(ws + 335544320ull);         //  32 MB  x bf16
    u16* whh   = (u16*)(ws + 369098752ull);         //   8 MB
    u16* wih   = (u16*)(ws + 377487360ull);         //   4 MB
    u16* wkv   = (u16*)(ws + 381681664ull);         //   2 MB  [Wkey;Wval]
    u32* flags = (u32*)(ws + 383778816ull);         //   8 KB  barrier flags

    cast_bf16_kernel<<<1024, 256, 0, stream>>>(x, xb, 32 * 1024 * 512);
    cast_bf16_kernel<<<256, 256, 0, stream>>>(W_ih, wih, 4096 * 512);
    cast_bf16_kernel<<<256, 256, 0, stream>>>(W_hh, whh, 4096 * 1024);
    cast_bf16_kernel<<<64, 256, 0, stream>>>(W_key, wkv, 512 * 1024);
    cast_bf16_kernel<<<64, 256, 0, stream>>>(W_val, wkv + 512 * 1024, 512 * 1024);
    init_flags_kernel<<<8, 256, 0, stream>>>(flags);

    // phase 1: xg = x @ W_ih^T + b_ih + b_hh  (row+col permuted bf16)
    gemm_tn<<<dim3(4096 / BN, 32768 / BM), 256, 0, stream>>>(
        xb, wih, 32768, 4096, 512, b_ih, b_hh, xg, nullptr, 1);

    // phase 2: recurrence — 64 blocks, REGULAR launch (trivially co-resident)
    lstm_rec<<<dim3(64), dim3(256), 0, stream>>>(whh, xg, hs, flags);

    // phase 3: keys/values = hs @ [Wkey;Wval]^T + bias
    gemm_tn<<<dim3(1024 / BN, 32768 / BM), 256, 0, stream>>>(
        hs, wkv, 32768, 1024, 1024, b_key, b_val, nullptr, out, 2);
}